// Round 1
// baseline (314.336 us; speedup 1.0000x reference)
//
#include <hip/hip_runtime.h>
#include <hip/hip_bf16.h>
#include <hip/hip_fp16.h>
#include <cstdint>

typedef _Float16 f16;
typedef _Float16 f16x8 __attribute__((ext_vector_type(8)));
typedef float f32x4 __attribute__((ext_vector_type(4)));

constexpr int D_MODEL = 1024;
constexpr int NH = 16;
constexpr int DH = 64;
constexpr int BATCH = 2;
constexpr int SEQ = 2048;
constexpr int NTOK = BATCH * SEQ;  // 4096

static __device__ __forceinline__ void gld_lds16(const void* g, void* l) {
  __builtin_amdgcn_global_load_lds(
      (__attribute__((address_space(1))) void*)(g),
      (__attribute__((address_space(3))) void*)(l), 16, 0, 0);
}

// ---------------- convert kernels ----------------

__global__ void cvt_x(const float* __restrict__ x, f16* __restrict__ xh) {
  int i = blockIdx.x * blockDim.x + threadIdx.x;  // each handles 8 elems
  const float4* p = reinterpret_cast<const float4*>(x) + (size_t)i * 2;
  float4 a = p[0], b = p[1];
  f16x8 o;
  o[0] = (f16)a.x; o[1] = (f16)a.y; o[2] = (f16)a.z; o[3] = (f16)a.w;
  o[4] = (f16)b.x; o[5] = (f16)b.y; o[6] = (f16)b.z; o[7] = (f16)b.w;
  *reinterpret_cast<f16x8*>(xh + (size_t)i * 8) = o;
}

// transpose-convert: dst[n][k] = (f16)src[k][n], 32x32 tiles
__global__ void cvt_w(const float* __restrict__ Wq, const float* __restrict__ Wk,
                      const float* __restrict__ Wv, const float* __restrict__ Wo,
                      f16* __restrict__ Wqkvt, f16* __restrict__ Wot) {
  __shared__ float tile[32][33];
  int z = blockIdx.z;
  const float* src = (z == 0) ? Wq : (z == 1) ? Wk : (z == 2) ? Wv : Wo;
  f16* dst = (z < 3) ? (Wqkvt + (size_t)z * D_MODEL * D_MODEL) : Wot;
  int n0 = blockIdx.x * 32, k0 = blockIdx.y * 32;
  int tx = threadIdx.x & 31, ty = threadIdx.x >> 5;  // ty in [0,8)
#pragma unroll
  for (int j = 0; j < 32; j += 8)
    tile[ty + j][tx] = src[(size_t)(k0 + ty + j) * D_MODEL + n0 + tx];
  __syncthreads();
#pragma unroll
  for (int j = 0; j < 32; j += 8)
    dst[(size_t)(n0 + ty + j) * D_MODEL + k0 + tx] = (f16)tile[tx][ty + j];
}

// ---------------- 128x128 GEMM (m97 structure), A[M][K] fp16, Bt[N][K] fp16 ----
// MODE 0: QKV epilogue (bias + rotary + scale -> fp16 q/k/v in [B*H][S][DH])
// MODE 1: out-proj epilogue (bias -> fp32 d_out)

template <int MODE>
__global__ __launch_bounds__(256, 2) void gemm128(
    const f16* __restrict__ A, const f16* __restrict__ Bt,
    const float* __restrict__ b0, const float* __restrict__ b1,
    const float* __restrict__ b2, const float* __restrict__ rot,
    f16* __restrict__ oq, f16* __restrict__ ok, f16* __restrict__ ov,
    float* __restrict__ oOut) {
  constexpr int K = 1024;
  constexpr int BK = 64;
  __shared__ __align__(16) f16 As[128 * BK];
  __shared__ __align__(16) f16 Bs[128 * BK];
  const int tid = threadIdx.x;
  const int w = tid >> 6, lane = tid & 63;
  const int m0 = blockIdx.y * 128, n0 = blockIdx.x * 128;
  const int wr = (w >> 1) * 64, wc = (w & 1) * 64;
  const int lr = lane & 15, lg = lane >> 4;

  f32x4 acc[4][4] = {};

  auto stage = [&](int kt) {
#pragma unroll
    for (int i = 0; i < 4; ++i) {
      int seg = (w * 4 + i) * 64 + lane;
      int row = seg >> 3, col = (seg & 7) * 8;
      gld_lds16(A + (size_t)(m0 + row) * K + kt + col, &As[seg * 8]);
      gld_lds16(Bt + (size_t)(n0 + row) * K + kt + col, &Bs[seg * 8]);
    }
  };

  stage(0);
#pragma unroll 1
  for (int kt = 0; kt < K; kt += BK) {
    __syncthreads();
#pragma unroll
    for (int kk = 0; kk < BK; kk += 32) {
      f16x8 af[4], bf[4];
#pragma unroll
      for (int mi = 0; mi < 4; ++mi)
        af[mi] = *reinterpret_cast<const f16x8*>(&As[(wr + mi * 16 + lr) * BK + kk + lg * 8]);
#pragma unroll
      for (int ni = 0; ni < 4; ++ni)
        bf[ni] = *reinterpret_cast<const f16x8*>(&Bs[(wc + ni * 16 + lr) * BK + kk + lg * 8]);
#pragma unroll
      for (int mi = 0; mi < 4; ++mi)
#pragma unroll
        for (int ni = 0; ni < 4; ++ni)
          acc[mi][ni] = __builtin_amdgcn_mfma_f32_16x16x32_f16(af[mi], bf[ni], acc[mi][ni], 0, 0, 0);
    }
    __syncthreads();
    if (kt + BK < K) stage(kt + BK);
  }

#pragma unroll
  for (int mi = 0; mi < 4; ++mi) {
    int rowb = m0 + wr + mi * 16 + lg * 4;
#pragma unroll
    for (int ni = 0; ni < 4; ++ni) {
      int col = n0 + wc + ni * 16 + lr;
#pragma unroll
      for (int r = 0; r < 4; ++r) {
        float val = acc[mi][ni][r];
        int m = rowb + r;
        if (MODE == 0) {
          int which = col >> 10, rest = col & 1023;
          int hh = rest >> 6, d = rest & 63;
          int bb = m >> 11, ss = m & 2047;
          size_t dst = ((size_t)(bb * NH + hh) * SEQ + ss) * DH + d;
          if (which == 0) {
            oq[dst] = (f16)((val + b0[rest] + rot[d]) * 0.125f);
          } else if (which == 1) {
            ok[dst] = (f16)(val + b1[rest]);
          } else {
            ov[dst] = (f16)(val + b2[rest]);
          }
        } else {
          oOut[(size_t)m * D_MODEL + col] = val + b0[col];
        }
      }
    }
  }
}

// ---------------- flash attention ----------------
// grid: (SEQ/64, BATCH*NH); block 256 (4 waves x 16 q-rows)
__global__ __launch_bounds__(256, 2) void attn(
    const f16* __restrict__ Qg, const f16* __restrict__ Kg,
    const f16* __restrict__ Vg, f16* __restrict__ Og) {
  __shared__ __align__(16) f16 Ks[64 * 64];
  __shared__ __align__(16) f16 Vt[64 * 72];  // transposed V tile, padded stride 72
  __shared__ __align__(16) f16 Ps[4][16 * 64];
  const int tid = threadIdx.x, w = tid >> 6, lane = tid & 63;
  const int lr = lane & 15, lg = lane >> 4;
  const int bh = blockIdx.y;
  const int q0 = blockIdx.x * 64 + w * 16;
  const f16* Qb = Qg + (size_t)bh * SEQ * DH;
  const f16* Kb = Kg + (size_t)bh * SEQ * DH;
  const f16* Vb = Vg + (size_t)bh * SEQ * DH;

  // Q fragments (held in regs for the whole loop); Q is pre-scaled by 1/8
  f16x8 aq[2];
#pragma unroll
  for (int ks = 0; ks < 2; ++ks)
    aq[ks] = *reinterpret_cast<const f16x8*>(Qb + (size_t)(q0 + lr) * DH + ks * 32 + lg * 8);

  float mi[4], li[4];
  f32x4 accO[4] = {};
#pragma unroll
  for (int r = 0; r < 4; ++r) { mi[r] = -1e30f; li[r] = 0.f; }

#pragma unroll 1
  for (int t = 0; t < SEQ; t += 64) {
    // stage K tile via global_load_lds (64x64 fp16 = 512 x 16B segments)
#pragma unroll
    for (int i = 0; i < 2; ++i) {
      int seg = (w * 2 + i) * 64 + lane;
      int row = seg >> 3, col = (seg & 7) * 8;
      gld_lds16(Kb + (size_t)(t + row) * DH + col, &Ks[seg * 8]);
    }
    // stage V transposed (reg path)
    {
      int vr = tid >> 2, vc0 = (tid & 3) * 16;
      f16x8 v0 = *reinterpret_cast<const f16x8*>(Vb + (size_t)(t + vr) * DH + vc0);
      f16x8 v1 = *reinterpret_cast<const f16x8*>(Vb + (size_t)(t + vr) * DH + vc0 + 8);
#pragma unroll
      for (int i2 = 0; i2 < 8; ++i2) {
        Vt[(vc0 + i2) * 72 + vr] = v0[i2];
        Vt[(vc0 + 8 + i2) * 72 + vr] = v1[i2];
      }
    }
    __syncthreads();

    // S = Q K^T  (per wave: 16q x 64k)
    f32x4 sc[4];
#pragma unroll
    for (int kt2 = 0; kt2 < 4; ++kt2) {
      f32x4 z = {};
#pragma unroll
      for (int ks = 0; ks < 2; ++ks) {
        f16x8 bk8 = *reinterpret_cast<const f16x8*>(&Ks[(kt2 * 16 + lr) * 64 + ks * 32 + lg * 8]);
        z = __builtin_amdgcn_mfma_f32_16x16x32_f16(aq[ks], bk8, z, 0, 0, 0);
      }
      sc[kt2] = z;
    }

    // online softmax (fragment rows: q = lg*4 + r, col k = kt2*16 + lr)
    float pm[4];
#pragma unroll
    for (int r = 0; r < 4; ++r)
      pm[r] = fmaxf(fmaxf(sc[0][r], sc[1][r]), fmaxf(sc[2][r], sc[3][r]));
#pragma unroll
    for (int x = 1; x < 16; x <<= 1)
#pragma unroll
      for (int r = 0; r < 4; ++r)
        pm[r] = fmaxf(pm[r], __shfl_xor(pm[r], x, 64));
    float scale[4];
#pragma unroll
    for (int r = 0; r < 4; ++r) {
      float nm = fmaxf(mi[r], pm[r]);
      scale[r] = __expf(mi[r] - nm);
      mi[r] = nm;
    }
    float rs[4] = {0.f, 0.f, 0.f, 0.f};
#pragma unroll
    for (int kt2 = 0; kt2 < 4; ++kt2)
#pragma unroll
      for (int r = 0; r < 4; ++r) {
        float p = __expf(sc[kt2][r] - mi[r]);
        rs[r] += p;
        Ps[w][(lg * 4 + r) * 64 + kt2 * 16 + lr] = (f16)p;
      }
#pragma unroll
    for (int x = 1; x < 16; x <<= 1)
#pragma unroll
      for (int r = 0; r < 4; ++r)
        rs[r] += __shfl_xor(rs[r], x, 64);
#pragma unroll
    for (int r = 0; r < 4; ++r)
      li[r] = li[r] * scale[r] + rs[r];
#pragma unroll
    for (int ct = 0; ct < 4; ++ct)
#pragma unroll
      for (int r = 0; r < 4; ++r)
        accO[ct][r] *= scale[r];

    // O += P V   (per wave: 16q x 64d)
#pragma unroll
    for (int ks = 0; ks < 2; ++ks) {
      f16x8 ap = *reinterpret_cast<const f16x8*>(&Ps[w][lr * 64 + ks * 32 + lg * 8]);
#pragma unroll
      for (int ct = 0; ct < 4; ++ct) {
        f16x8 bv = *reinterpret_cast<const f16x8*>(&Vt[(ct * 16 + lr) * 72 + ks * 32 + lg * 8]);
        accO[ct] = __builtin_amdgcn_mfma_f32_16x16x32_f16(ap, bv, accO[ct], 0, 0, 0);
      }
    }
    __syncthreads();
  }

  // epilogue: O /= l, write [tok][D_MODEL]
  const int bb = bh >> 4, hh = bh & 15;
#pragma unroll
  for (int r = 0; r < 4; ++r) {
    float inv = 1.f / li[r];
    int sq = q0 + lg * 4 + r;
    f16* dst = Og + (size_t)(bb * SEQ + sq) * D_MODEL + hh * DH;
#pragma unroll
    for (int ct = 0; ct < 4; ++ct)
      dst[ct * 16 + lr] = (f16)(accO[ct][r] * inv);
  }
}

// ---------------- launch ----------------

extern "C" void kernel_launch(void* const* d_in, const int* in_sizes, int n_in,
                              void* d_out, int out_size, void* d_ws, size_t ws_size,
                              hipStream_t stream) {
  const float* x  = (const float*)d_in[0];
  const float* Wq = (const float*)d_in[1];
  const float* bq = (const float*)d_in[2];
  const float* Wk = (const float*)d_in[3];
  const float* bk = (const float*)d_in[4];
  const float* Wv = (const float*)d_in[5];
  const float* bv = (const float*)d_in[6];
  const float* Wo = (const float*)d_in[7];
  const float* bo = (const float*)d_in[8];
  const float* rot = (const float*)d_in[9];

  char* wsb = (char*)d_ws;
  f16* Xh    = (f16*)(wsb);                         // 8 MB  [4096][1024]
  f16* Wqkvt = (f16*)(wsb + ((size_t)8 << 20));     // 6 MB  [3072][1024] (transposed)
  f16* Wot   = (f16*)(wsb + ((size_t)14 << 20));    // 2 MB  [1024][1024] (transposed)
  f16* Qa    = (f16*)(wsb + ((size_t)16 << 20));    // 8 MB  [32][2048][64]
  f16* Ka    = (f16*)(wsb + ((size_t)24 << 20));    // 8 MB
  f16* Va    = (f16*)(wsb + ((size_t)32 << 20));    // 8 MB
  f16* Oa    = (f16*)(wsb + ((size_t)40 << 20));    // 8 MB  [4096][1024]

  cvt_x<<<dim3(NTOK * D_MODEL / (8 * 256)), dim3(256), 0, stream>>>(x, Xh);
  cvt_w<<<dim3(32, 32, 4), dim3(256), 0, stream>>>(Wq, Wk, Wv, Wo, Wqkvt, Wot);

  gemm128<0><<<dim3(3 * D_MODEL / 128, NTOK / 128), dim3(256), 0, stream>>>(
      Xh, Wqkvt, bq, bk, bv, rot, Qa, Ka, Va, nullptr);

  attn<<<dim3(SEQ / 64, BATCH * NH), dim3(256), 0, stream>>>(Qa, Ka, Va, Oa);

  gemm128<1><<<dim3(D_MODEL / 128, NTOK / 128), dim3(256), 0, stream>>>(
      Oa, Wot, bo, nullptr, nullptr, nullptr, nullptr, nullptr, nullptr,
      (float*)d_out);
}

// Round 2
// 269.632 us; speedup vs baseline: 1.1658x; 1.1658x over previous
//
#include <hip/hip_runtime.h>
#include <hip/hip_bf16.h>
#include <hip/hip_fp16.h>
#include <cstdint>

typedef _Float16 f16;
typedef _Float16 f16x8 __attribute__((ext_vector_type(8)));
typedef float f32x4 __attribute__((ext_vector_type(4)));

constexpr int D_MODEL = 1024;
constexpr int NH = 16;
constexpr int DH = 64;
constexpr int BATCH = 2;
constexpr int SEQ = 2048;
constexpr int NTOK = BATCH * SEQ;  // 4096

static __device__ __forceinline__ void gld_lds16(const void* g, void* l) {
  __builtin_amdgcn_global_load_lds(
      (__attribute__((address_space(1))) void*)(g),
      (__attribute__((address_space(3))) void*)(l), 16, 0, 0);
}

// ---------------- convert kernels ----------------

__global__ void cvt_x(const float* __restrict__ x, f16* __restrict__ xh) {
  int i = blockIdx.x * blockDim.x + threadIdx.x;  // each handles 8 elems
  const float4* p = reinterpret_cast<const float4*>(x) + (size_t)i * 2;
  float4 a = p[0], b = p[1];
  f16x8 o;
  o[0] = (f16)a.x; o[1] = (f16)a.y; o[2] = (f16)a.z; o[3] = (f16)a.w;
  o[4] = (f16)b.x; o[5] = (f16)b.y; o[6] = (f16)b.z; o[7] = (f16)b.w;
  *reinterpret_cast<f16x8*>(xh + (size_t)i * 8) = o;
}

// transpose-convert: dst[n][k] = (f16)src[k][n], 32x32 tiles
__global__ void cvt_w(const float* __restrict__ Wq, const float* __restrict__ Wk,
                      const float* __restrict__ Wv, const float* __restrict__ Wo,
                      f16* __restrict__ Wqkvt, f16* __restrict__ Wot) {
  __shared__ float tile[32][33];
  int z = blockIdx.z;
  const float* src = (z == 0) ? Wq : (z == 1) ? Wk : (z == 2) ? Wv : Wo;
  f16* dst = (z < 3) ? (Wqkvt + (size_t)z * D_MODEL * D_MODEL) : Wot;
  int n0 = blockIdx.x * 32, k0 = blockIdx.y * 32;
  int tx = threadIdx.x & 31, ty = threadIdx.x >> 5;  // ty in [0,8)
#pragma unroll
  for (int j = 0; j < 32; j += 8)
    tile[ty + j][tx] = src[(size_t)(k0 + ty + j) * D_MODEL + n0 + tx];
  __syncthreads();
#pragma unroll
  for (int j = 0; j < 32; j += 8)
    dst[(size_t)(n0 + ty + j) * D_MODEL + k0 + tx] = (f16)tile[tx][ty + j];
}

// V [32][2048][64] -> Vt [32][64][2048]; 64x64 f16 tiles, swizzled LDS.
// LDS swizzle: 16B-chunk index ^= (d&7) ^ ((d>>3)&7) so scalar transposed
// writes AND vector reads both spread across banks.
__global__ void transpose_v(const f16* __restrict__ V, f16* __restrict__ Vt) {
  __shared__ __align__(16) f16 t[64 * 64];
  const int bh = blockIdx.y, s0 = blockIdx.x * 64;
  const f16* src = V + ((size_t)bh * SEQ + s0) * DH;
  f16* dst = Vt + (size_t)bh * DH * SEQ + s0;
  const int i = threadIdx.x;  // 256 threads
#pragma unroll
  for (int p = 0; p < 2; ++p) {
    int seg = p * 256 + i;
    int s = seg >> 3, d0 = (seg & 7) * 8;
    f16x8 v = *reinterpret_cast<const f16x8*>(src + (size_t)s * DH + d0);
#pragma unroll
    for (int j = 0; j < 8; ++j) {
      int d = d0 + j;
      int swz = ((s >> 3) ^ (d & 7) ^ ((d >> 3) & 7)) & 7;
      t[d * 64 + swz * 8 + (s & 7)] = v[j];
    }
  }
  __syncthreads();
#pragma unroll
  for (int p = 0; p < 2; ++p) {
    int seg = p * 256 + i;
    int d = seg >> 3, c0 = (seg & 7) * 8;
    int swz = ((c0 >> 3) ^ (d & 7) ^ ((d >> 3) & 7)) & 7;
    f16x8 v = *reinterpret_cast<const f16x8*>(&t[d * 64 + swz * 8]);
    *reinterpret_cast<f16x8*>(dst + (size_t)d * SEQ + c0) = v;
  }
}

// ---------------- 128x128 GEMM (m97 structure), A[M][K] fp16, Bt[N][K] fp16 ----
// MODE 0: QKV epilogue (bias + rotary + scale*log2e -> fp16 q/k/v)
// MODE 1: out-proj epilogue (bias -> fp32 d_out)

template <int MODE>
__global__ __launch_bounds__(256, 2) void gemm128(
    const f16* __restrict__ A, const f16* __restrict__ Bt,
    const float* __restrict__ b0, const float* __restrict__ b1,
    const float* __restrict__ b2, const float* __restrict__ rot,
    f16* __restrict__ oq, f16* __restrict__ ok, f16* __restrict__ ov,
    float* __restrict__ oOut) {
  constexpr int K = 1024;
  constexpr int BK = 64;
  __shared__ __align__(16) f16 As[128 * BK];
  __shared__ __align__(16) f16 Bs[128 * BK];
  const int tid = threadIdx.x;
  const int w = tid >> 6, lane = tid & 63;
  const int m0 = blockIdx.y * 128, n0 = blockIdx.x * 128;
  const int wr = (w >> 1) * 64, wc = (w & 1) * 64;
  const int lr = lane & 15, lg = lane >> 4;

  f32x4 acc[4][4] = {};

  auto stage = [&](int kt) {
#pragma unroll
    for (int i = 0; i < 4; ++i) {
      int seg = (w * 4 + i) * 64 + lane;
      int row = seg >> 3, col = (seg & 7) * 8;
      gld_lds16(A + (size_t)(m0 + row) * K + kt + col, &As[seg * 8]);
      gld_lds16(Bt + (size_t)(n0 + row) * K + kt + col, &Bs[seg * 8]);
    }
  };

  stage(0);
#pragma unroll 1
  for (int kt = 0; kt < K; kt += BK) {
    __syncthreads();
#pragma unroll
    for (int kk = 0; kk < BK; kk += 32) {
      f16x8 af[4], bf[4];
#pragma unroll
      for (int mi = 0; mi < 4; ++mi)
        af[mi] = *reinterpret_cast<const f16x8*>(&As[(wr + mi * 16 + lr) * BK + kk + lg * 8]);
#pragma unroll
      for (int ni = 0; ni < 4; ++ni)
        bf[ni] = *reinterpret_cast<const f16x8*>(&Bs[(wc + ni * 16 + lr) * BK + kk + lg * 8]);
#pragma unroll
      for (int mi = 0; mi < 4; ++mi)
#pragma unroll
        for (int ni = 0; ni < 4; ++ni)
          acc[mi][ni] = __builtin_amdgcn_mfma_f32_16x16x32_f16(af[mi], bf[ni], acc[mi][ni], 0, 0, 0);
    }
    __syncthreads();
    if (kt + BK < K) stage(kt + BK);
  }

#pragma unroll
  for (int mi = 0; mi < 4; ++mi) {
    int rowb = m0 + wr + mi * 16 + lg * 4;
#pragma unroll
    for (int ni = 0; ni < 4; ++ni) {
      int col = n0 + wc + ni * 16 + lr;
#pragma unroll
      for (int r = 0; r < 4; ++r) {
        float val = acc[mi][ni][r];
        int m = rowb + r;
        if (MODE == 0) {
          int which = col >> 10, rest = col & 1023;
          int hh = rest >> 6, d = rest & 63;
          int bb = m >> 11, ss = m & 2047;
          size_t dst = ((size_t)(bb * NH + hh) * SEQ + ss) * DH + d;
          if (which == 0) {
            // fold softmax scale AND log2(e) (exp2-domain softmax) into Q
            oq[dst] = (f16)((val + b0[rest] + rot[d]) * (0.125f * 1.4426950408889634f));
          } else if (which == 1) {
            ok[dst] = (f16)(val + b1[rest]);
          } else {
            ov[dst] = (f16)(val + b2[rest]);
          }
        } else {
          oOut[(size_t)m * D_MODEL + col] = val + b0[col];
        }
      }
    }
  }
}

// ---------------- flash attention ----------------
// grid: (SEQ/64, BATCH*NH); block 256 (4 waves x 16 q-rows)
// K/V^T staged via global_load_lds with source-chunk XOR swizzle
// (phys_chunk = chunk ^ (row&7)); reads apply the same XOR -> conflict-free.
__global__ __launch_bounds__(256, 4) void attn(
    const f16* __restrict__ Qg, const f16* __restrict__ Kg,
    const f16* __restrict__ Vtg, f16* __restrict__ Og) {
  __shared__ __align__(16) f16 Ks[2][64 * 64];   // rows = kv, cols = d
  __shared__ __align__(16) f16 Vs[2][64 * 64];   // rows = d,  cols = kv
  __shared__ __align__(16) f16 Ps[4][16 * 64];   // per-wave P tile (swizzled)
  const int tid = threadIdx.x, w = tid >> 6, lane = tid & 63;
  const int lr = lane & 15, lg = lane >> 4;
  const int bh = blockIdx.y;
  const int q0 = blockIdx.x * 64 + w * 16;
  const f16* Qb = Qg + (size_t)bh * SEQ * DH;
  const f16* Kb = Kg + (size_t)bh * SEQ * DH;
  const f16* Vtb = Vtg + (size_t)bh * DH * SEQ;

  // Q fragments (pre-scaled by 0.125*log2e in GEMM epilogue)
  f16x8 aq[2];
#pragma unroll
  for (int ks = 0; ks < 2; ++ks)
    aq[ks] = *reinterpret_cast<const f16x8*>(Qb + (size_t)(q0 + lr) * DH + ks * 32 + lg * 8);

  float mi[4], li[4];
  f32x4 accO[4] = {};
#pragma unroll
  for (int r = 0; r < 4; ++r) { mi[r] = -1e30f; li[r] = 0.f; }

  auto stage = [&](int buf, int t) {
#pragma unroll
    for (int i = 0; i < 2; ++i) {
      int seg = (w * 2 + i) * 64 + lane;            // 0..511
      int row = seg >> 3, c = seg & 7;
      int sc8 = (c ^ (row & 7)) * 8;
      gld_lds16(Kb + (size_t)(t + row) * DH + sc8, &Ks[buf][seg * 8]);
      gld_lds16(Vtb + (size_t)row * SEQ + t + sc8, &Vs[buf][seg * 8]);
    }
  };

  stage(0, 0);
  int cur = 0;
#pragma unroll 1
  for (int t = 0; t < SEQ; t += 64) {
    __syncthreads();  // buf[cur] staged (barrier drains vmcnt), buf[cur^1] free
    if (t + 64 < SEQ) stage(cur ^ 1, t + 64);

    // S = Q K^T  (per wave: 16q x 64k)
    f32x4 sc[4];
#pragma unroll
    for (int kt2 = 0; kt2 < 4; ++kt2) {
      f32x4 z = {};
#pragma unroll
      for (int ks = 0; ks < 2; ++ks) {
        f16x8 bk8 = *reinterpret_cast<const f16x8*>(
            &Ks[cur][(kt2 * 16 + lr) * 64 + ((ks * 4 + lg) ^ (lr & 7)) * 8]);
        z = __builtin_amdgcn_mfma_f32_16x16x32_f16(aq[ks], bk8, z, 0, 0, 0);
      }
      sc[kt2] = z;
    }

    // online softmax in exp2 domain (rows: q = lg*4 + r, col k = kt2*16 + lr)
    float pm[4];
#pragma unroll
    for (int r = 0; r < 4; ++r)
      pm[r] = fmaxf(fmaxf(sc[0][r], sc[1][r]), fmaxf(sc[2][r], sc[3][r]));
#pragma unroll
    for (int x = 1; x < 16; x <<= 1)
#pragma unroll
      for (int r = 0; r < 4; ++r)
        pm[r] = fmaxf(pm[r], __shfl_xor(pm[r], x, 64));
    float scale[4];
#pragma unroll
    for (int r = 0; r < 4; ++r) {
      float nm = fmaxf(mi[r], pm[r]);
      scale[r] = __builtin_amdgcn_exp2f(mi[r] - nm);
      mi[r] = nm;
    }
    float rs[4] = {0.f, 0.f, 0.f, 0.f};
#pragma unroll
    for (int kt2 = 0; kt2 < 4; ++kt2)
#pragma unroll
      for (int r = 0; r < 4; ++r) {
        float p = __builtin_amdgcn_exp2f(sc[kt2][r] - mi[r]);
        rs[r] += p;
        int qrow = lg * 4 + r;
        int phys = (kt2 * 2 + (lr >> 3)) ^ (qrow & 7);
        Ps[w][qrow * 64 + phys * 8 + (lr & 7)] = (f16)p;
      }
#pragma unroll
    for (int x = 1; x < 16; x <<= 1)
#pragma unroll
      for (int r = 0; r < 4; ++r)
        rs[r] += __shfl_xor(rs[r], x, 64);
#pragma unroll
    for (int r = 0; r < 4; ++r)
      li[r] = li[r] * scale[r] + rs[r];
#pragma unroll
    for (int ct = 0; ct < 4; ++ct)
#pragma unroll
      for (int r = 0; r < 4; ++r)
        accO[ct][r] *= scale[r];

    // O += P V   (per wave: 16q x 64d); Vs rows = d, cols = kv
#pragma unroll
    for (int ks = 0; ks < 2; ++ks) {
      f16x8 ap = *reinterpret_cast<const f16x8*>(
          &Ps[w][lr * 64 + ((ks * 4 + lg) ^ (lr & 7)) * 8]);
#pragma unroll
      for (int ct = 0; ct < 4; ++ct) {
        f16x8 bv = *reinterpret_cast<const f16x8*>(
            &Vs[cur][(ct * 16 + lr) * 64 + ((ks * 4 + lg) ^ (lr & 7)) * 8]);
        accO[ct] = __builtin_amdgcn_mfma_f32_16x16x32_f16(ap, bv, accO[ct], 0, 0, 0);
      }
    }
    cur ^= 1;
  }

  // epilogue: O /= l, write [tok][D_MODEL]
  const int bb = bh >> 4, hh = bh & 15;
#pragma unroll
  for (int r = 0; r < 4; ++r) {
    float inv = 1.f / li[r];
    int sq = q0 + lg * 4 + r;
    f16* dst = Og + (size_t)(bb * SEQ + sq) * D_MODEL + hh * DH;
#pragma unroll
    for (int ct = 0; ct < 4; ++ct)
      dst[ct * 16 + lr] = (f16)(accO[ct][r] * inv);
  }
}

// ---------------- launch ----------------

extern "C" void kernel_launch(void* const* d_in, const int* in_sizes, int n_in,
                              void* d_out, int out_size, void* d_ws, size_t ws_size,
                              hipStream_t stream) {
  const float* x  = (const float*)d_in[0];
  const float* Wq = (const float*)d_in[1];
  const float* bq = (const float*)d_in[2];
  const float* Wk = (const float*)d_in[3];
  const float* bk = (const float*)d_in[4];
  const float* Wv = (const float*)d_in[5];
  const float* bv = (const float*)d_in[6];
  const float* Wo = (const float*)d_in[7];
  const float* bo = (const float*)d_in[8];
  const float* rot = (const float*)d_in[9];

  char* wsb = (char*)d_ws;
  f16* Xh    = (f16*)(wsb);                         // 8 MB  [4096][1024]
  f16* Wqkvt = (f16*)(wsb + ((size_t)8 << 20));     // 6 MB  [3072][1024] (transposed)
  f16* Wot   = (f16*)(wsb + ((size_t)14 << 20));    // 2 MB  [1024][1024] (transposed)
  f16* Qa    = (f16*)(wsb + ((size_t)16 << 20));    // 8 MB  [32][2048][64]
  f16* Ka    = (f16*)(wsb + ((size_t)24 << 20));    // 8 MB
  f16* Va    = (f16*)(wsb + ((size_t)32 << 20));    // 8 MB
  f16* Oa    = (f16*)(wsb + ((size_t)40 << 20));    // 8 MB  [4096][1024]
  f16* Vta   = (f16*)(wsb + ((size_t)48 << 20));    // 8 MB  [32][64][2048]

  cvt_x<<<dim3(NTOK * D_MODEL / (8 * 256)), dim3(256), 0, stream>>>(x, Xh);
  cvt_w<<<dim3(32, 32, 4), dim3(256), 0, stream>>>(Wq, Wk, Wv, Wo, Wqkvt, Wot);

  gemm128<0><<<dim3(3 * D_MODEL / 128, NTOK / 128), dim3(256), 0, stream>>>(
      Xh, Wqkvt, bq, bk, bv, rot, Qa, Ka, Va, nullptr);

  transpose_v<<<dim3(SEQ / 64, BATCH * NH), dim3(256), 0, stream>>>(Va, Vta);

  attn<<<dim3(SEQ / 64, BATCH * NH), dim3(256), 0, stream>>>(Qa, Ka, Vta, Oa);

  gemm128<1><<<dim3(D_MODEL / 128, NTOK / 128), dim3(256), 0, stream>>>(
      Oa, Wot, bo, nullptr, nullptr, nullptr, nullptr, nullptr, nullptr,
      (float*)d_out);
}

// Round 5
// 222.304 us; speedup vs baseline: 1.4140x; 1.2129x over previous
//
#include <hip/hip_runtime.h>
#include <hip/hip_bf16.h>
#include <hip/hip_fp16.h>
#include <cstdint>

typedef _Float16 f16;
typedef _Float16 f16x4 __attribute__((ext_vector_type(4)));
typedef _Float16 f16x8 __attribute__((ext_vector_type(8)));
typedef __fp16 h16x2 __attribute__((ext_vector_type(2)));
typedef float f32x4 __attribute__((ext_vector_type(4)));

constexpr int D_MODEL = 1024;
constexpr int NH = 16;
constexpr int DH = 64;
constexpr int BATCH = 2;
constexpr int SEQ = 2048;
constexpr int NTOK = BATCH * SEQ;  // 4096

static __device__ __forceinline__ void gld_lds16(const void* g, void* l) {
  __builtin_amdgcn_global_load_lds(
      (__attribute__((address_space(1))) void*)(g),
      (__attribute__((address_space(3))) void*)(l), 16, 0, 0);
}

// pack 4 floats -> f16x4 via two v_cvt_pkrtz_f16_f32
static __device__ __forceinline__ f16x4 pack4(float a, float b, float c, float d) {
  h16x2 lo = __builtin_amdgcn_cvt_pkrtz(a, b);
  h16x2 hi = __builtin_amdgcn_cvt_pkrtz(c, d);
  struct { h16x2 x, y; } pr{lo, hi};
  return __builtin_bit_cast(f16x4, pr);
}

// ---------------- convert kernels ----------------

__global__ void cvt_x(const float* __restrict__ x, f16* __restrict__ xh) {
  int i = blockIdx.x * blockDim.x + threadIdx.x;  // each handles 8 elems
  const float4* p = reinterpret_cast<const float4*>(x) + (size_t)i * 2;
  float4 a = p[0], b = p[1];
  f16x8 o;
  o[0] = (f16)a.x; o[1] = (f16)a.y; o[2] = (f16)a.z; o[3] = (f16)a.w;
  o[4] = (f16)b.x; o[5] = (f16)b.y; o[6] = (f16)b.z; o[7] = (f16)b.w;
  *reinterpret_cast<f16x8*>(xh + (size_t)i * 8) = o;
}

// transpose-convert: dst[n][k] = (f16)src[k][n], 32x32 tiles
__global__ void cvt_w(const float* __restrict__ Wq, const float* __restrict__ Wk,
                      const float* __restrict__ Wv, const float* __restrict__ Wo,
                      f16* __restrict__ Wqkvt, f16* __restrict__ Wot) {
  __shared__ float tile[32][33];
  int z = blockIdx.z;
  const float* src = (z == 0) ? Wq : (z == 1) ? Wk : (z == 2) ? Wv : Wo;
  f16* dst = (z < 3) ? (Wqkvt + (size_t)z * D_MODEL * D_MODEL) : Wot;
  int n0 = blockIdx.x * 32, k0 = blockIdx.y * 32;
  int tx = threadIdx.x & 31, ty = threadIdx.x >> 5;  // ty in [0,8)
#pragma unroll
  for (int j = 0; j < 32; j += 8)
    tile[ty + j][tx] = src[(size_t)(k0 + ty + j) * D_MODEL + n0 + tx];
  __syncthreads();
#pragma unroll
  for (int j = 0; j < 32; j += 8)
    dst[(size_t)(n0 + ty + j) * D_MODEL + k0 + tx] = (f16)tile[tx][ty + j];
}

// V [32][2048][64] -> Vt [32][64][2048]; 64x64 f16 tiles, swizzled LDS.
__global__ void transpose_v(const f16* __restrict__ V, f16* __restrict__ Vt) {
  __shared__ __align__(16) f16 t[64 * 64];
  const int bh = blockIdx.y, s0 = blockIdx.x * 64;
  const f16* src = V + ((size_t)bh * SEQ + s0) * DH;
  f16* dst = Vt + (size_t)bh * DH * SEQ + s0;
  const int i = threadIdx.x;  // 256 threads
#pragma unroll
  for (int p = 0; p < 2; ++p) {
    int seg = p * 256 + i;
    int s = seg >> 3, d0 = (seg & 7) * 8;
    f16x8 v = *reinterpret_cast<const f16x8*>(src + (size_t)s * DH + d0);
#pragma unroll
    for (int j = 0; j < 8; ++j) {
      int d = d0 + j;
      int swz = ((s >> 3) ^ (d & 7) ^ ((d >> 3) & 7)) & 7;
      t[d * 64 + swz * 8 + (s & 7)] = v[j];
    }
  }
  __syncthreads();
#pragma unroll
  for (int p = 0; p < 2; ++p) {
    int seg = p * 256 + i;
    int d = seg >> 3, c0 = (seg & 7) * 8;
    int swz = ((c0 >> 3) ^ (d & 7) ^ ((d >> 3) & 7)) & 7;
    f16x8 v = *reinterpret_cast<const f16x8*>(&t[d * 64 + swz * 8]);
    *reinterpret_cast<f16x8*>(dst + (size_t)d * SEQ + c0) = v;
  }
}

// ---------------- 128x128 GEMM (m97 structure), A[M][K] fp16, Bt[N][K] fp16 ----
// MODE 0: QKV epilogue (bias + rotary + scale*log2e -> fp16 q/k/v)
// MODE 1: out-proj epilogue (bias -> fp32 d_out)
// grid is flattened with a column-grouped XCD swizzle (gy hardcoded = 32).

template <int MODE>
__global__ __launch_bounds__(256, 2) void gemm128(
    const f16* __restrict__ A, const f16* __restrict__ Bt,
    const float* __restrict__ b0, const float* __restrict__ b1,
    const float* __restrict__ b2, const float* __restrict__ rot,
    f16* __restrict__ oq, f16* __restrict__ ok, f16* __restrict__ ov,
    float* __restrict__ oOut) {
  constexpr int K = 1024;
  constexpr int BK = 64;
  __shared__ __align__(16) f16 As[128 * BK];
  __shared__ __align__(16) f16 Bs[128 * BK];
  const int tid = threadIdx.x;
  const int w = tid >> 6, lane = tid & 63;
  // XCD swizzle: tot divisible by 8; each XCD gets a contiguous chunk of nf ->
  // column-major grouping (consecutive nf share bx -> B-panel L2-resident).
  const int tot = gridDim.x;  // FIXED (was gridDim.x*32 -> OOB crash)
  const int flat = blockIdx.x;
  const int nf = (flat & 7) * (tot >> 3) + (flat >> 3);
  const int bx = nf >> 5, by = nf & 31;  // gy == 32 hardcoded
  const int m0 = by * 128, n0 = bx * 128;
  const int wr = (w >> 1) * 64, wc = (w & 1) * 64;
  const int lr = lane & 15, lg = lane >> 4;

  f32x4 acc[4][4] = {};

  auto stage = [&](int kt) {
#pragma unroll
    for (int i = 0; i < 4; ++i) {
      int seg = (w * 4 + i) * 64 + lane;
      int row = seg >> 3, col = (seg & 7) * 8;
      gld_lds16(A + (size_t)(m0 + row) * K + kt + col, &As[seg * 8]);
      gld_lds16(Bt + (size_t)(n0 + row) * K + kt + col, &Bs[seg * 8]);
    }
  };

  stage(0);
#pragma unroll 1
  for (int kt = 0; kt < K; kt += BK) {
    __syncthreads();
#pragma unroll
    for (int kk = 0; kk < BK; kk += 32) {
      f16x8 af[4], bf[4];
#pragma unroll
      for (int mi = 0; mi < 4; ++mi)
        af[mi] = *reinterpret_cast<const f16x8*>(&As[(wr + mi * 16 + lr) * BK + kk + lg * 8]);
#pragma unroll
      for (int ni = 0; ni < 4; ++ni)
        bf[ni] = *reinterpret_cast<const f16x8*>(&Bs[(wc + ni * 16 + lr) * BK + kk + lg * 8]);
#pragma unroll
      for (int mi = 0; mi < 4; ++mi)
#pragma unroll
        for (int ni = 0; ni < 4; ++ni)
          acc[mi][ni] = __builtin_amdgcn_mfma_f32_16x16x32_f16(af[mi], bf[ni], acc[mi][ni], 0, 0, 0);
    }
    __syncthreads();
    if (kt + BK < K) stage(kt + BK);
  }

#pragma unroll
  for (int mi = 0; mi < 4; ++mi) {
    int rowb = m0 + wr + mi * 16 + lg * 4;
#pragma unroll
    for (int ni = 0; ni < 4; ++ni) {
      int col = n0 + wc + ni * 16 + lr;
#pragma unroll
      for (int r = 0; r < 4; ++r) {
        float val = acc[mi][ni][r];
        int m = rowb + r;
        if (MODE == 0) {
          int which = col >> 10, rest = col & 1023;
          int hh = rest >> 6, d = rest & 63;
          int bb = m >> 11, ss = m & 2047;
          size_t dst = ((size_t)(bb * NH + hh) * SEQ + ss) * DH + d;
          if (which == 0) {
            // fold softmax scale AND log2(e) (exp2-domain softmax) into Q
            oq[dst] = (f16)((val + b0[rest] + rot[d]) * (0.125f * 1.4426950408889634f));
          } else if (which == 1) {
            ok[dst] = (f16)(val + b1[rest]);
          } else {
            ov[dst] = (f16)(val + b2[rest]);
          }
        } else {
          oOut[(size_t)m * D_MODEL + col] = val + b0[col];
        }
      }
    }
  }
}

// ---------------- flash attention ----------------
// 1024 blocks (1-D), 256 thr = 4 waves x 16 q-rows.
// XCD swizzle: xcd=b&7 gets heads {4*xcd..4*xcd+3} -> K/V (2MB) L2-resident.
// Swapped-operand MFMA: S^T = mfma(K,Q) puts a q-row's 16 scores in ONE lane
// (q = lane&15) -> in-lane softmax, 2 shuffles per reduction, P packed with
// cvt_pkrtz into 4x ds_write_b64. PV: O^T = mfma(V^T, P) -> per-lane rescale.
__global__ __launch_bounds__(256, 4) void attn(
    const f16* __restrict__ Qg, const f16* __restrict__ Kg,
    const f16* __restrict__ Vtg, f16* __restrict__ Og) {
  __shared__ __align__(16) f16 Ks[2][64 * 64];   // rows = kv, cols = d (swizzled chunks)
  __shared__ __align__(16) f16 Vs[2][64 * 64];   // rows = d,  cols = kv (swizzled chunks)
  __shared__ __align__(16) f16 Ps[4][16 * 64];   // per-wave P tile (swizzled)
  const int tid = threadIdx.x, w = tid >> 6, lane = tid & 63;
  const int lr = lane & 15, lg = lane >> 4;
  // block swizzle
  const int b = blockIdx.x;
  const int xcd = b & 7, j = b >> 3;
  const int bh = xcd * 4 + (j & 3);
  const int qb = j >> 2;
  const int q0 = qb * 64 + w * 16;
  const f16* Qb = Qg + (size_t)bh * SEQ * DH;
  const f16* Kb = Kg + (size_t)bh * SEQ * DH;
  const f16* Vtb = Vtg + (size_t)bh * DH * SEQ;

  // Q fragments (pre-scaled by 0.125*log2e); B-operand: lane holds Q[q=lr][d]
  f16x8 aq[2];
#pragma unroll
  for (int ks = 0; ks < 2; ++ks)
    aq[ks] = *reinterpret_cast<const f16x8*>(Qb + (size_t)(q0 + lr) * DH + ks * 32 + lg * 8);

  float mi = -1e30f, li = 0.f;
  f32x4 accO[4] = {};  // accO[ct][r] = O[q=lr][d=ct*16+lg*4+r]

  auto stage = [&](int buf, int t) {
#pragma unroll
    for (int i = 0; i < 2; ++i) {
      int seg = (w * 2 + i) * 64 + lane;            // 0..511
      int row = seg >> 3, c = seg & 7;
      int sc8 = (c ^ (row & 7)) * 8;
      gld_lds16(Kb + (size_t)(t + row) * DH + sc8, &Ks[buf][seg * 8]);
      gld_lds16(Vtb + (size_t)row * SEQ + t + sc8, &Vs[buf][seg * 8]);
    }
  };

  stage(0, 0);
  int cur = 0;
#pragma unroll 1
  for (int t = 0; t < SEQ; t += 64) {
    __syncthreads();  // buf[cur] staged (barrier drains vmcnt), buf[cur^1] free
    if (t + 64 < SEQ) stage(cur ^ 1, t + 64);

    // S^T = K Q^T : sc[kt2][r] = S[q=lr][kv=kt2*16+lg*4+r]
    f32x4 sc[4];
#pragma unroll
    for (int kt2 = 0; kt2 < 4; ++kt2) {
      f32x4 z = {};
#pragma unroll
      for (int ks = 0; ks < 2; ++ks) {
        f16x8 kf = *reinterpret_cast<const f16x8*>(
            &Ks[cur][(kt2 * 16 + lr) * 64 + ((ks * 4 + lg) ^ (lr & 7)) * 8]);
        z = __builtin_amdgcn_mfma_f32_16x16x32_f16(kf, aq[ks], z, 0, 0, 0);
      }
      sc[kt2] = z;
    }

    // in-lane softmax over this lane's 16 scores (all same q-row)
    float pm = sc[0][0];
#pragma unroll
    for (int kt2 = 0; kt2 < 4; ++kt2)
#pragma unroll
      for (int r = 0; r < 4; ++r) pm = fmaxf(pm, sc[kt2][r]);
    pm = fmaxf(pm, __shfl_xor(pm, 16));
    pm = fmaxf(pm, __shfl_xor(pm, 32));
    // defer-max: only rescale when max grew by more than 8 (exp2 domain)
    if (!__all(pm <= mi + 8.f)) {
      float nm = fmaxf(mi, pm);
      float sc8 = __builtin_amdgcn_exp2f(mi - nm);
      mi = nm;
      li *= sc8;
#pragma unroll
      for (int ct = 0; ct < 4; ++ct)
#pragma unroll
        for (int r = 0; r < 4; ++r) accO[ct][r] *= sc8;
    }
    // P = exp2(S - mi), row-sum, pack to LDS
    float rs = 0.f;
#pragma unroll
    for (int kt2 = 0; kt2 < 4; ++kt2)
#pragma unroll
      for (int r = 0; r < 4; ++r) {
        float p = __builtin_amdgcn_exp2f(sc[kt2][r] - mi);
        sc[kt2][r] = p;
        rs += p;
      }
    rs += __shfl_xor(rs, 16);
    rs += __shfl_xor(rs, 32);
    li += rs;
#pragma unroll
    for (int kt2 = 0; kt2 < 4; ++kt2) {
      f16x4 pk = pack4(sc[kt2][0], sc[kt2][1], sc[kt2][2], sc[kt2][3]);
      // row q=lr, 16B chunk c16 = kt2*2+(lg>>1), phys = c16^(lr&7), half lg&1
      int addr = lr * 64 + (((kt2 * 2 + (lg >> 1)) ^ (lr & 7)) * 8) + (lg & 1) * 4;
      *reinterpret_cast<f16x4*>(&Ps[w][addr]) = pk;
    }

    // O^T += V^T P^T : accO[ct] = mfma(V^T frag, P frag)
#pragma unroll
    for (int ks = 0; ks < 2; ++ks) {
      f16x8 ap = *reinterpret_cast<const f16x8*>(
          &Ps[w][lr * 64 + ((ks * 4 + lg) ^ (lr & 7)) * 8]);
#pragma unroll
      for (int ct = 0; ct < 4; ++ct) {
        f16x8 bv = *reinterpret_cast<const f16x8*>(
            &Vs[cur][(ct * 16 + lr) * 64 + ((ks * 4 + lg) ^ (lr & 7)) * 8]);
        accO[ct] = __builtin_amdgcn_mfma_f32_16x16x32_f16(bv, ap, accO[ct], 0, 0, 0);
      }
    }
    cur ^= 1;
  }

  // epilogue: O /= l; lane holds q=lr, d = ct*16 + lg*4 + r
  const int bb = bh >> 4, hh = bh & 15;
  float inv = 1.f / li;
  f16* dst = Og + (size_t)(bb * SEQ + q0 + lr) * D_MODEL + hh * DH;
#pragma unroll
  for (int ct = 0; ct < 4; ++ct) {
    f16x4 pk = pack4(accO[ct][0] * inv, accO[ct][1] * inv,
                     accO[ct][2] * inv, accO[ct][3] * inv);
    *reinterpret_cast<f16x4*>(dst + ct * 16 + lg * 4) = pk;
  }
}

// ---------------- launch ----------------

extern "C" void kernel_launch(void* const* d_in, const int* in_sizes, int n_in,
                              void* d_out, int out_size, void* d_ws, size_t ws_size,
                              hipStream_t stream) {
  const float* x  = (const float*)d_in[0];
  const float* Wq = (const float*)d_in[1];
  const float* bq = (const float*)d_in[2];
  const float* Wk = (const float*)d_in[3];
  const float* bk = (const float*)d_in[4];
  const float* Wv = (const float*)d_in[5];
  const float* bv = (const float*)d_in[6];
  const float* Wo = (const float*)d_in[7];
  const float* bo = (const float*)d_in[8];
  const float* rot = (const float*)d_in[9];

  char* wsb = (char*)d_ws;
  f16* Xh    = (f16*)(wsb);                         // 8 MB  [4096][1024]
  f16* Wqkvt = (f16*)(wsb + ((size_t)8 << 20));     // 6 MB  [3072][1024] (transposed)
  f16* Wot   = (f16*)(wsb + ((size_t)14 << 20));    // 2 MB  [1024][1024] (transposed)
  f16* Qa    = (f16*)(wsb + ((size_t)16 << 20));    // 8 MB  [32][2048][64]
  f16* Ka    = (f16*)(wsb + ((size_t)24 << 20));    // 8 MB
  f16* Va    = (f16*)(wsb + ((size_t)32 << 20));    // 8 MB
  f16* Oa    = (f16*)(wsb + ((size_t)40 << 20));    // 8 MB  [4096][1024]
  f16* Vta   = (f16*)(wsb + ((size_t)48 << 20));    // 8 MB  [32][64][2048]

  cvt_x<<<dim3(NTOK * D_MODEL / (8 * 256)), dim3(256), 0, stream>>>(x, Xh);
  cvt_w<<<dim3(32, 32, 4), dim3(256), 0, stream>>>(Wq, Wk, Wv, Wo, Wqkvt, Wot);

  gemm128<0><<<dim3(3 * D_MODEL / 128 * (NTOK / 128)), dim3(256), 0, stream>>>(
      Xh, Wqkvt, bq, bk, bv, rot, Qa, Ka, Va, nullptr);

  transpose_v<<<dim3(SEQ / 64, BATCH * NH), dim3(256), 0, stream>>>(Va, Vta);

  attn<<<dim3((SEQ / 64) * BATCH * NH), dim3(256), 0, stream>>>(Qa, Ka, Vta, Oa);

  gemm128<1><<<dim3(D_MODEL / 128 * (NTOK / 128)), dim3(256), 0, stream>>>(
      Oa, Wot, bo, nullptr, nullptr, nullptr, nullptr, nullptr, nullptr,
      (float*)d_out);
}